// Round 9
// baseline (272.713 us; speedup 1.0000x reference)
//
#include <hip/hip_runtime.h>

typedef __bf16 bf16x8 __attribute__((ext_vector_type(8)));
typedef __bf16 bf16x4 __attribute__((ext_vector_type(4)));
typedef float f32x4 __attribute__((ext_vector_type(4)));
typedef float f32x16 __attribute__((ext_vector_type(16)));

__device__ __forceinline__ f32x4 mfma16(bf16x8 a, bf16x8 b, f32x4 c) {
  return __builtin_amdgcn_mfma_f32_16x16x32_bf16(a, b, c, 0, 0, 0);
}
__device__ __forceinline__ f32x16 mfma32(bf16x8 a, bf16x8 b, f32x16 c) {
  return __builtin_amdgcn_mfma_f32_32x32x16_bf16(a, b, c, 0, 0, 0);
}

// pack 2 fp32 -> u32 of 2 bf16 (compiler fuses to v_cvt_pk_bf16_f32, m240)
__device__ __forceinline__ unsigned int cvtpk(float a, float b) {
  union { __bf16 h[2]; unsigned int u; } r;
  r.h[0] = (__bf16)a; r.h[1] = (__bf16)b;
  return r.u;
}
// v_permlane32_swap_b32: exchange across the 32-lane halves
__device__ __forceinline__ void swap32(unsigned int &a, unsigned int &b) {
  asm("v_permlane32_swap_b32 %0, %1" : "+v"(a), "+v"(b));
}

// ---------------------------------------------------------------------------
// K0: convert Wf(32x256) | Wg(32x256) | Wh(256x256) fp32 -> Wb bf16 [320][256]
// ---------------------------------------------------------------------------
__global__ void wcvt_kernel(const float* __restrict__ Wf, const float* __restrict__ Wg,
                            const float* __restrict__ Wh, __bf16* __restrict__ Wb) {
  int i = blockIdx.x * 256 + threadIdx.x;  // 0..81919
  float v;
  if (i < 8192)       v = Wf[i];
  else if (i < 16384) v = Wg[i - 8192];
  else                v = Wh[i - 16384];
  Wb[i] = (__bf16)v;
}

// ---------------------------------------------------------------------------
// K1: projections (unchanged, round-7 form).
// ---------------------------------------------------------------------------
__global__ __launch_bounds__(512) void proj_kernel(
    const float* __restrict__ x, const float* __restrict__ bfv,
    const float* __restrict__ bgv, const float* __restrict__ bhv,
    const __bf16* __restrict__ Wb, __bf16* __restrict__ qkpk,
    __bf16* __restrict__ vpk) {
  __shared__ __align__(16) char smem[2560 + 18432];
  __bf16* xT = (__bf16*)smem;           // [32 n][40 c] bf16
  __bf16* ho = (__bf16*)(smem + 2560);  // [256 c][36 n] bf16

  const int t = threadIdx.x;
  const int l = t & 63, wg = t >> 6, q = l >> 4, l15 = l & 15;
  const int nh = wg & 1, oh = wg >> 1;   // oh 0..3
  const int bi = blockIdx.x;
  const int b = bi >> 7;
  const int nt = bi & 127;               // 32-row n tile
  const int n0 = nt << 5;

  const float* xb = x + (size_t)b * 256 * 4096;

  f32x4 acc[5];
#pragma unroll
  for (int i = 0; i < 5; i++) acc[i] = (f32x4){0.f, 0.f, 0.f, 0.f};

  const int c_rel = t >> 4;        // 0..31
  const int n2 = (t & 15) * 2;     // 0..30

#pragma unroll 1
  for (int kc = 0; kc < 8; kc++) {
    __syncthreads();
    float2 v = *(const float2*)(xb + (size_t)(kc * 32 + c_rel) * 4096 + n0 + n2);
    xT[(n2 + 0) * 40 + c_rel] = (__bf16)v.x;
    xT[(n2 + 1) * 40 + c_rel] = (__bf16)v.y;
    __syncthreads();
    bf16x8 af = *(const bf16x8*)(xT + (nh * 16 + l15) * 40 + q * 8);
    const __bf16* wp = Wb + (size_t)(oh * 80 + l15) * 256 + kc * 32 + q * 8;
#pragma unroll
    for (int ot = 0; ot < 5; ot++) {
      bf16x8 bfr = *(const bf16x8*)(wp + (size_t)ot * 16 * 256);
      acc[ot] = mfma16(af, bfr, acc[ot]);
    }
  }

#pragma unroll
  for (int ot = 0; ot < 5; ot++) {
    int o = oh * 80 + ot * 16 + l15;
    float bias = (o < 32) ? bfv[o] : (o < 64) ? bgv[o - 32] : bhv[o - 64];
    if (oh == 0 && ot < 4) {
      int qk = o >> 5, fr = (o >> 4) & 1, hh = (o >> 3) & 1, e = o & 7;
      size_t base = ((size_t)b * 128 + nt) * 2048 + qk * 1024 + fr * 512 + hh * 256;
#pragma unroll
      for (int r = 0; r < 4; r++) {
        int n_rel = nh * 16 + q * 4 + r;
        qkpk[base + n_rel * 8 + e] = (__bf16)(acc[ot][r] + bias);
      }
    } else {
#pragma unroll
      for (int r = 0; r < 4; r++) {
        int n_rel = nh * 16 + q * 4 + r;
        ho[(o - 64) * 36 + n_rel] = (__bf16)(acc[ot][r] + bias);
      }
    }
  }
  __syncthreads();
  unsigned short* vpku = (unsigned short*)vpk + (size_t)b * 1048576;
  const unsigned short* hou = (const unsigned short*)ho;
  for (int e = t; e < 4096; e += 512) {
    int c = e >> 4, nn = (e & 15) * 2;
    int n = n0 + nn;
    int jc = n >> 4, hh = (n >> 3) & 1, ee = n & 7;
    unsigned int vv = *(const unsigned int*)(hou + c * 36 + nn);
    *(unsigned int*)(vpku + (((size_t)(jc * 2 + hh) * 256 + c) * 8 + ee)) = vv;
  }
}

// ---------------------------------------------------------------------------
// K2a ABLATION A (noV): identical to attn but V loaded ONCE before the loop;
// per-chunk V loads removed. Writes garbage to pO/Lp (overwritten by real
// attn). Measures: kernel time without the per-chunk V register-load path.
// ---------------------------------------------------------------------------
__global__ __launch_bounds__(512, 2) void attn_ablA_noV(
    const __bf16* __restrict__ qkpk, const __bf16* __restrict__ vpk,
    __bf16* __restrict__ pO, float* __restrict__ Lp) {
  __shared__ __align__(16) char smem[139264];

  const int t = threadIdx.x;
  const int l = t & 63, w = t >> 6;
  const int h = l >> 5, l31 = l & 31;

  const int bi = blockIdx.x;
  const int xcd = bi & 7;
  const int combo = xcd * 2 + ((bi >> 3) & 1);
  const int ig = bi >> 4;
  const int b = combo >> 2, jp = combo & 3;
  const int ti = ig * 8 + w;
  const int n0 = ti << 5;

  const __bf16* qkb = qkpk + (size_t)b * 262144;
  const __bf16* vpb = vpk + (size_t)b * 1048576;
  const int jq0 = jp << 10;

  const __bf16* qp = qkb + (size_t)ti * 2048 + h * 256 + l31 * 8;
  const bf16x8 qf0 = *(const bf16x8*)(qp);
  const bf16x8 qf1 = *(const bf16x8*)(qp + 512);

  f32x16 acc[8] = {};
  float rsum = 0.f;

  const __bf16* kbase = qkb + 1024 + h * 256 + l31 * 8;
  const int vlane = h * 2048 + l31 * 8;

  bf16x8 kf0 = *(const bf16x8*)(kbase + (size_t)(jq0 >> 5) * 2048);
  bf16x8 kf1 = *(const bf16x8*)(kbase + (size_t)(jq0 >> 5) * 2048 + 512);

  // V hoisted: chunk-0 tiles only, reused every chunk (ablation)
  bf16x8 vb0[8], vb1[8];
  {
    const __bf16* vchunk = vpb + (size_t)(jq0 >> 4) * 4096 + vlane;
#pragma unroll
    for (int ct = 0; ct < 8; ct++) {
      vb0[ct] = *(const bf16x8*)(vchunk + ct * 256);
      vb1[ct] = *(const bf16x8*)(vchunk + 4096 + ct * 256);
    }
  }

#pragma unroll 1
  for (int ch = 0; ch < 32; ++ch) {
    f32x16 s = {};
    s = mfma32(kf0, qf0, s);
    s = mfma32(kf1, qf1, s);

    if (ch < 31) {
      const __bf16* kp = kbase + (size_t)((jq0 >> 5) + ch + 1) * 2048;
      kf0 = *(const bf16x8*)(kp);
      kf1 = *(const bf16x8*)(kp + 512);
    }

    float p[16];
#pragma unroll
    for (int r = 0; r < 16; r++) { p[r] = __expf(s[r]); rsum += p[r]; }

    unsigned int u0 = cvtpk(p[0], p[1]), v0 = cvtpk(p[2], p[3]);
    unsigned int w0 = cvtpk(p[4], p[5]), z0 = cvtpk(p[6], p[7]);
    swap32(u0, w0); swap32(v0, z0);
    unsigned int u1 = cvtpk(p[8], p[9]), v1 = cvtpk(p[10], p[11]);
    unsigned int w1 = cvtpk(p[12], p[13]), z1 = cvtpk(p[14], p[15]);
    swap32(u1, w1); swap32(v1, z1);
    union { unsigned int u[4]; bf16x8 v; } A0, A1;
    A0.u[0] = u0; A0.u[1] = v0; A0.u[2] = w0; A0.u[3] = z0;
    A1.u[0] = u1; A1.u[1] = v1; A1.u[2] = w1; A1.u[3] = z1;

#pragma unroll
    for (int ct = 0; ct < 8; ct++) acc[ct] = mfma32(A0.v, vb0[ct], acc[ct]);
#pragma unroll
    for (int ct = 0; ct < 8; ct++) acc[ct] = mfma32(A1.v, vb1[ct], acc[ct]);
  }

  __bf16* stage = (__bf16*)smem + (size_t)w * 8704;
#pragma unroll
  for (int ct = 0; ct < 8; ct++) {
    int c0 = ct * 32 + l31;
#pragma unroll
    for (int r = 0; r < 16; r++) {
      int i_loc = (r & 3) + 8 * (r >> 2) + 4 * h;
      stage[c0 * 34 + i_loc] = (__bf16)acc[ct][r];
    }
  }
  asm volatile("s_waitcnt lgkmcnt(0)" ::: "memory");

  unsigned short* ob = (unsigned short*)pO + (size_t)(jp * 4 + b) * 1048576 + n0;
  const unsigned short* su = (const unsigned short*)stage;
#pragma unroll 1
  for (int e = l; e < 4096; e += 64) {
    int c = e >> 4, i2 = (e & 15) * 2;
    unsigned int vv = *(const unsigned int*)(su + c * 34 + i2);
    *(unsigned int*)(ob + (size_t)c * 4096 + i2) = vv;
  }
  rsum += __shfl_xor(rsum, 32);
  if (l < 32) Lp[(size_t)(jp * 4 + b) * 4096 + n0 + l] = rsum;
}

// ---------------------------------------------------------------------------
// K2b ABLATION B (noSpine): QK-mfma/exp/pack/K-loads removed; A-fragments
// taken from Q registers. Per-chunk V loads + 16 PV mfma intact. Writes
// garbage to pO/Lp (overwritten). Measures: the V+PV machine alone.
// ---------------------------------------------------------------------------
__global__ __launch_bounds__(512, 2) void attn_ablB_noSpine(
    const __bf16* __restrict__ qkpk, const __bf16* __restrict__ vpk,
    __bf16* __restrict__ pO, float* __restrict__ Lp) {
  __shared__ __align__(16) char smem[139264];

  const int t = threadIdx.x;
  const int l = t & 63, w = t >> 6;
  const int h = l >> 5, l31 = l & 31;

  const int bi = blockIdx.x;
  const int xcd = bi & 7;
  const int combo = xcd * 2 + ((bi >> 3) & 1);
  const int ig = bi >> 4;
  const int b = combo >> 2, jp = combo & 3;
  const int ti = ig * 8 + w;
  const int n0 = ti << 5;

  const __bf16* qkb = qkpk + (size_t)b * 262144;
  const __bf16* vpb = vpk + (size_t)b * 1048576;
  const int jq0 = jp << 10;

  const __bf16* qp = qkb + (size_t)ti * 2048 + h * 256 + l31 * 8;
  const bf16x8 qf0 = *(const bf16x8*)(qp);
  const bf16x8 qf1 = *(const bf16x8*)(qp + 512);

  f32x16 acc[8] = {};
  const int vlane = h * 2048 + l31 * 8;

#pragma unroll 1
  for (int ch = 0; ch < 32; ++ch) {
    const __bf16* vchunk = vpb + (size_t)((jq0 >> 4) + ch * 2) * 4096 + vlane;
    bf16x8 vb0[8];
#pragma unroll
    for (int ct = 0; ct < 8; ct++)
      vb0[ct] = *(const bf16x8*)(vchunk + ct * 256);
    bf16x8 vb1[8];
#pragma unroll
    for (int ct = 0; ct < 8; ct++)
      vb1[ct] = *(const bf16x8*)(vchunk + 4096 + ct * 256);

#pragma unroll
    for (int ct = 0; ct < 8; ct++) acc[ct] = mfma32(qf0, vb0[ct], acc[ct]);
#pragma unroll
    for (int ct = 0; ct < 8; ct++) acc[ct] = mfma32(qf1, vb1[ct], acc[ct]);
  }

  __bf16* stage = (__bf16*)smem + (size_t)w * 8704;
#pragma unroll
  for (int ct = 0; ct < 8; ct++) {
    int c0 = ct * 32 + l31;
#pragma unroll
    for (int r = 0; r < 16; r++) {
      int i_loc = (r & 3) + 8 * (r >> 2) + 4 * h;
      stage[c0 * 34 + i_loc] = (__bf16)acc[ct][r];
    }
  }
  asm volatile("s_waitcnt lgkmcnt(0)" ::: "memory");

  unsigned short* ob = (unsigned short*)pO + (size_t)(jp * 4 + b) * 1048576 + n0;
  const unsigned short* su = (const unsigned short*)stage;
#pragma unroll 1
  for (int e = l; e < 4096; e += 64) {
    int c = e >> 4, i2 = (e & 15) * 2;
    unsigned int vv = *(const unsigned int*)(su + c * 34 + i2);
    *(unsigned int*)(ob + (size_t)c * 4096 + i2) = vv;
  }
  if (l < 32) Lp[(size_t)(jp * 4 + b) * 4096 + n0 + l] = 1.0f;
}

// ---------------------------------------------------------------------------
// K2: fused attention — round-7 structure, unchanged (the REAL pass; runs
// after the ablations and overwrites every byte of pO/Lp they touched).
// ---------------------------------------------------------------------------
__global__ __launch_bounds__(512, 2) void attn_kernel(
    const __bf16* __restrict__ qkpk, const __bf16* __restrict__ vpk,
    __bf16* __restrict__ pO, float* __restrict__ Lp) {
  __shared__ __align__(16) char smem[139264];  // 8 waves x [256 c][34 i] bf16

  const int t = threadIdx.x;
  const int l = t & 63, w = t >> 6;          // 8 waves
  const int h = l >> 5, l31 = l & 31;

  const int bi = blockIdx.x;
  const int xcd = bi & 7;
  const int combo = xcd * 2 + ((bi >> 3) & 1);  // (b,jp) pinned to one XCD
  const int ig = bi >> 4;                       // 0..15
  const int b = combo >> 2, jp = combo & 3;
  const int ti = ig * 8 + w;                    // i-tile 0..127
  const int n0 = ti << 5;

  const __bf16* qkb = qkpk + (size_t)b * 262144;
  const __bf16* vpb = vpk + (size_t)b * 1048576;
  const int jq0 = jp << 10;

  const __bf16* qp = qkb + (size_t)ti * 2048 + h * 256 + l31 * 8;
  const bf16x8 qf0 = *(const bf16x8*)(qp);
  const bf16x8 qf1 = *(const bf16x8*)(qp + 512);

  f32x16 acc[8] = {};                        // [ct] -> c = ct*32 + l31
  float rsum = 0.f;

  const __bf16* kbase = qkb + 1024 + h * 256 + l31 * 8;
  const int vlane = h * 2048 + l31 * 8;

  bf16x8 kf0 = *(const bf16x8*)(kbase + (size_t)(jq0 >> 5) * 2048);
  bf16x8 kf1 = *(const bf16x8*)(kbase + (size_t)(jq0 >> 5) * 2048 + 512);

#pragma unroll 1
  for (int ch = 0; ch < 32; ++ch) {
    f32x16 s = {};
    s = mfma32(kf0, qf0, s);
    s = mfma32(kf1, qf1, s);

    if (ch < 31) {
      const __bf16* kp = kbase + (size_t)((jq0 >> 5) + ch + 1) * 2048;
      kf0 = *(const bf16x8*)(kp);
      kf1 = *(const bf16x8*)(kp + 512);
    }

    const __bf16* vchunk = vpb + (size_t)((jq0 >> 4) + ch * 2) * 4096 + vlane;
    bf16x8 vb0[8];
#pragma unroll
    for (int ct = 0; ct < 8; ct++)
      vb0[ct] = *(const bf16x8*)(vchunk + ct * 256);

    float p[16];
#pragma unroll
    for (int r = 0; r < 16; r++) { p[r] = __expf(s[r]); rsum += p[r]; }

    unsigned int u0 = cvtpk(p[0], p[1]), v0 = cvtpk(p[2], p[3]);
    unsigned int w0 = cvtpk(p[4], p[5]), z0 = cvtpk(p[6], p[7]);
    swap32(u0, w0); swap32(v0, z0);
    unsigned int u1 = cvtpk(p[8], p[9]), v1 = cvtpk(p[10], p[11]);
    unsigned int w1 = cvtpk(p[12], p[13]), z1 = cvtpk(p[14], p[15]);
    swap32(u1, w1); swap32(v1, z1);
    union { unsigned int u[4]; bf16x8 v; } A0, A1;
    A0.u[0] = u0; A0.u[1] = v0; A0.u[2] = w0; A0.u[3] = z0;
    A1.u[0] = u1; A1.u[1] = v1; A1.u[2] = w1; A1.u[3] = z1;

    bf16x8 vb1[8];
#pragma unroll
    for (int ct = 0; ct < 8; ct++)
      vb1[ct] = *(const bf16x8*)(vchunk + 4096 + ct * 256);

#pragma unroll
    for (int ct = 0; ct < 8; ct++) acc[ct] = mfma32(A0.v, vb0[ct], acc[ct]);
#pragma unroll
    for (int ct = 0; ct < 8; ct++) acc[ct] = mfma32(A1.v, vb1[ct], acc[ct]);
  }

  __bf16* stage = (__bf16*)smem + (size_t)w * 8704;
#pragma unroll
  for (int ct = 0; ct < 8; ct++) {
    int c0 = ct * 32 + l31;
#pragma unroll
    for (int r = 0; r < 16; r++) {
      int i_loc = (r & 3) + 8 * (r >> 2) + 4 * h;
      stage[c0 * 34 + i_loc] = (__bf16)acc[ct][r];
    }
  }
  asm volatile("s_waitcnt lgkmcnt(0)" ::: "memory");  // wave-local, no barrier

  unsigned short* ob = (unsigned short*)pO + (size_t)(jp * 4 + b) * 1048576 + n0;
  const unsigned short* su = (const unsigned short*)stage;
#pragma unroll 1
  for (int e = l; e < 4096; e += 64) {
    int c = e >> 4, i2 = (e & 15) * 2;
    unsigned int vv = *(const unsigned int*)(su + c * 34 + i2);
    *(unsigned int*)(ob + (size_t)c * 4096 + i2) = vv;
  }

  rsum += __shfl_xor(rsum, 32);
  if (l < 32) Lp[(size_t)(jp * 4 + b) * 4096 + n0 + l] = rsum;
}

// ---------------------------------------------------------------------------
// K3: combine partials + normalize + residual (round-7 form, nt reverted).
// ---------------------------------------------------------------------------
__global__ __launch_bounds__(256) void norm_kernel(
    const float* __restrict__ x, const float* __restrict__ gamma_p,
    const __bf16* __restrict__ pO, const float* __restrict__ Lp,
    float* __restrict__ out) {
  const int bc = blockIdx.x;           // b = bc>>8, c = bc&255
  const int b = bc >> 8;
  const float gm = gamma_p[0];
  const float* xr = x + (size_t)bc * 4096;
  float* orow = out + (size_t)bc * 4096;
  const __bf16* pbase = pO + (size_t)bc * 4096;   // +jp*4194304
  const float* lbase = Lp + (size_t)b * 4096;     // +jp*16384

  for (int i0 = threadIdx.x * 4; i0 < 4096; i0 += 1024) {
    float4 xv = *(const float4*)(xr + i0);
    float s0 = 0.f, s1 = 0.f, s2 = 0.f, s3 = 0.f;
    float l0 = 0.f, l1 = 0.f, l2 = 0.f, l3 = 0.f;
#pragma unroll
    for (int jp = 0; jp < 4; jp++) {
      bf16x4 pv = *(const bf16x4*)(pbase + (size_t)jp * 4194304 + i0);
      s0 += (float)pv[0]; s1 += (float)pv[1]; s2 += (float)pv[2]; s3 += (float)pv[3];
      float4 lv = *(const float4*)(lbase + (size_t)jp * 16384 + i0);
      l0 += lv.x; l1 += lv.y; l2 += lv.z; l3 += lv.w;
    }
    float4 ov;
    ov.x = gm * s0 / l0 + xv.x;
    ov.y = gm * s1 / l1 + xv.y;
    ov.z = gm * s2 / l2 + xv.z;
    ov.w = gm * s3 / l3 + xv.w;
    *(float4*)(orow + i0) = ov;
  }
}

// ---------------------------------------------------------------------------
extern "C" void kernel_launch(void* const* d_in, const int* in_sizes, int n_in,
                              void* d_out, int out_size, void* d_ws, size_t ws_size,
                              hipStream_t stream) {
  const float* x   = (const float*)d_in[0];
  const float* Wf  = (const float*)d_in[1];
  const float* bfv = (const float*)d_in[2];
  const float* Wg  = (const float*)d_in[3];
  const float* bgv = (const float*)d_in[4];
  const float* Wh  = (const float*)d_in[5];
  const float* bhv = (const float*)d_in[6];
  const float* gm  = (const float*)d_in[7];
  float* out = (float*)d_out;

  char* ws = (char*)d_ws;
  __bf16* Wb   = (__bf16*)ws;                     //   160 KiB  @ 0
  __bf16* qkpk = (__bf16*)(ws + 262144);          //  2 MiB
  __bf16* vpk  = (__bf16*)(ws + 2359296);         //  8 MiB
  __bf16* pO   = (__bf16*)(ws + 10747904);        // 32 MiB
  float*  Lp   = (float*)(ws + 44302336);         // 256 KiB

  hipLaunchKernelGGL(wcvt_kernel, dim3(320), dim3(256), 0, stream, Wf, Wg, Wh, Wb);
  hipLaunchKernelGGL(proj_kernel, dim3(512), dim3(512), 0, stream,
                     x, bfv, bgv, bhv, Wb, qkpk, vpk);
  // diagnostic ablations (outputs fully overwritten by the real attn pass)
  hipLaunchKernelGGL(attn_ablA_noV, dim3(256), dim3(512), 0, stream,
                     qkpk, vpk, pO, Lp);
  hipLaunchKernelGGL(attn_ablB_noSpine, dim3(256), dim3(512), 0, stream,
                     qkpk, vpk, pO, Lp);
  hipLaunchKernelGGL(attn_kernel, dim3(256), dim3(512), 0, stream,
                     qkpk, vpk, pO, Lp);
  hipLaunchKernelGGL(norm_kernel, dim3(1024), dim3(256), 0, stream,
                     x, gm, pO, Lp, out);
}

// Round 11
// 161.039 us; speedup vs baseline: 1.6935x; 1.6935x over previous
//
#include <hip/hip_runtime.h>

typedef __bf16 bf16x8 __attribute__((ext_vector_type(8)));
typedef __bf16 bf16x4 __attribute__((ext_vector_type(4)));
typedef float f32x4 __attribute__((ext_vector_type(4)));
typedef float f32x16 __attribute__((ext_vector_type(16)));

__device__ __forceinline__ f32x4 mfma16(bf16x8 a, bf16x8 b, f32x4 c) {
  return __builtin_amdgcn_mfma_f32_16x16x32_bf16(a, b, c, 0, 0, 0);
}
__device__ __forceinline__ f32x16 mfma32(bf16x8 a, bf16x8 b, f32x16 c) {
  return __builtin_amdgcn_mfma_f32_32x32x16_bf16(a, b, c, 0, 0, 0);
}

// pack 2 fp32 -> u32 of 2 bf16 (compiler fuses to v_cvt_pk_bf16_f32)
__device__ __forceinline__ unsigned int cvtpk(float a, float b) {
  union { __bf16 h[2]; unsigned int u; } r;
  r.h[0] = (__bf16)a; r.h[1] = (__bf16)b;
  return r.u;
}
// v_permlane32_swap_b32: exchange across the 32-lane halves
__device__ __forceinline__ void swap32(unsigned int &a, unsigned int &b) {
  asm("v_permlane32_swap_b32 %0, %1" : "+v"(a), "+v"(b));
}

// Barrier that does NOT drain vmcnt: LDS ops fenced (lgkmcnt(0)), global
// prefetches (K regs, V stage loads) stay in flight across it (T4/T14).
__device__ __forceinline__ void sync_lds() {
  asm volatile("s_waitcnt lgkmcnt(0)" ::: "memory");
  __builtin_amdgcn_s_barrier();
}

// ---------------------------------------------------------------------------
// K0: convert Wf(32x256) | Wg(32x256) | Wh(256x256) fp32 -> Wb bf16 [320][256]
// ---------------------------------------------------------------------------
__global__ void wcvt_kernel(const float* __restrict__ Wf, const float* __restrict__ Wg,
                            const float* __restrict__ Wh, __bf16* __restrict__ Wb) {
  int i = blockIdx.x * 256 + threadIdx.x;  // 0..81919
  float v;
  if (i < 8192)       v = Wf[i];
  else if (i < 16384) v = Wg[i - 8192];
  else                v = Wh[i - 16384];
  Wb[i] = (__bf16)v;
}

// ---------------------------------------------------------------------------
// K1: projections (unchanged).
//   o<64  -> QK_pk[b][nt(128)][qk(2)][frag(2)][h(2)][r(32)][e(8)] bf16
//   o>=64 -> V_pk[b][jc(256)][h(2)][c(256)][e(8)] bf16 (via LDS transpose)
// ---------------------------------------------------------------------------
__global__ __launch_bounds__(512) void proj_kernel(
    const float* __restrict__ x, const float* __restrict__ bfv,
    const float* __restrict__ bgv, const float* __restrict__ bhv,
    const __bf16* __restrict__ Wb, __bf16* __restrict__ qkpk,
    __bf16* __restrict__ vpk) {
  __shared__ __align__(16) char smem[2560 + 18432];
  __bf16* xT = (__bf16*)smem;           // [32 n][40 c] bf16
  __bf16* ho = (__bf16*)(smem + 2560);  // [256 c][36 n] bf16

  const int t = threadIdx.x;
  const int l = t & 63, wg = t >> 6, q = l >> 4, l15 = l & 15;
  const int nh = wg & 1, oh = wg >> 1;   // oh 0..3
  const int bi = blockIdx.x;
  const int b = bi >> 7;
  const int nt = bi & 127;               // 32-row n tile
  const int n0 = nt << 5;

  const float* xb = x + (size_t)b * 256 * 4096;

  f32x4 acc[5];
#pragma unroll
  for (int i = 0; i < 5; i++) acc[i] = (f32x4){0.f, 0.f, 0.f, 0.f};

  const int c_rel = t >> 4;        // 0..31
  const int n2 = (t & 15) * 2;     // 0..30

#pragma unroll 1
  for (int kc = 0; kc < 8; kc++) {
    __syncthreads();
    float2 v = *(const float2*)(xb + (size_t)(kc * 32 + c_rel) * 4096 + n0 + n2);
    xT[(n2 + 0) * 40 + c_rel] = (__bf16)v.x;
    xT[(n2 + 1) * 40 + c_rel] = (__bf16)v.y;
    __syncthreads();
    bf16x8 af = *(const bf16x8*)(xT + (nh * 16 + l15) * 40 + q * 8);
    const __bf16* wp = Wb + (size_t)(oh * 80 + l15) * 256 + kc * 32 + q * 8;
#pragma unroll
    for (int ot = 0; ot < 5; ot++) {
      bf16x8 bfr = *(const bf16x8*)(wp + (size_t)ot * 16 * 256);
      acc[ot] = mfma16(af, bfr, acc[ot]);
    }
  }

#pragma unroll
  for (int ot = 0; ot < 5; ot++) {
    int o = oh * 80 + ot * 16 + l15;
    float bias = (o < 32) ? bfv[o] : (o < 64) ? bgv[o - 32] : bhv[o - 64];
    if (oh == 0 && ot < 4) {
      int qk = o >> 5, fr = (o >> 4) & 1, hh = (o >> 3) & 1, e = o & 7;
      size_t base = ((size_t)b * 128 + nt) * 2048 + qk * 1024 + fr * 512 + hh * 256;
#pragma unroll
      for (int r = 0; r < 4; r++) {
        int n_rel = nh * 16 + q * 4 + r;
        qkpk[base + n_rel * 8 + e] = (__bf16)(acc[ot][r] + bias);
      }
    } else {
#pragma unroll
      for (int r = 0; r < 4; r++) {
        int n_rel = nh * 16 + q * 4 + r;
        ho[(o - 64) * 36 + n_rel] = (__bf16)(acc[ot][r] + bias);
      }
    }
  }
  __syncthreads();
  unsigned short* vpku = (unsigned short*)vpk + (size_t)b * 1048576;
  const unsigned short* hou = (const unsigned short*)ho;
  for (int e = t; e < 4096; e += 512) {
    int c = e >> 4, nn = (e & 15) * 2;
    int n = n0 + nn;
    int jc = n >> 4, hh = (n >> 3) & 1, ee = n & 7;
    unsigned int vv = *(const unsigned int*)(hou + c * 36 + nn);
    *(unsigned int*)(vpku + (((size_t)(jc * 2 + hh) * 256 + c) * 8 + ee)) = vv;
  }
}

// ---------------------------------------------------------------------------
// K2: fused attention — P in registers (zero-LDS spine), V staged in LDS.
// Grid 256 = 16 (b,jp) combos x 16 i-groups, XCD-pinned; 512 thr = 8 waves,
// 1 block/CU. R9 ablation: per-chunk V register-loads were the wall (ablB
// V+PV alone = 76us > full 56.5; ablA noV = 34us). Fix: CU loads each 16KB
// V chunk from L2 ONCE (2 b128 loads/thread, issued at top, ds_written at
// bottom after the spine hides latency - T14), double-buffered in LDS
// (first 32KB of smem); waves ds_read_b128 their B-frags. L1 V traffic /8,
// vmem instrs/CU-chunk 128->32. Spine (QK->exp->pack) from round 7.
// R10 BUGFIX: epilogue stage slice is 8704 ELEMS (17408 B) per wave ->
// smem must be 139264 B and stride w*8704 elems (was w*4352: overlap).
// ---------------------------------------------------------------------------
__global__ __launch_bounds__(512, 2) void attn_kernel(
    const __bf16* __restrict__ qkpk, const __bf16* __restrict__ vpk,
    __bf16* __restrict__ pO, float* __restrict__ Lp) {
  // loop:    [0,32768) = V dbuf 2 x 16KB
  // epilogue: 8 waves x [256c][34i] bf16 = 139264 B (overlays V bufs; the
  //           final barrier drains all V reads before any stage write)
  __shared__ __align__(16) char smem[139264];
  __bf16* Vbuf = (__bf16*)smem;

  const int t = threadIdx.x;
  const int l = t & 63, w = t >> 6;          // 8 waves
  const int h = l >> 5, l31 = l & 31;

  const int bi = blockIdx.x;
  const int xcd = bi & 7;
  const int combo = xcd * 2 + ((bi >> 3) & 1);  // (b,jp) pinned to one XCD
  const int ig = bi >> 4;                       // 0..15
  const int b = combo >> 2, jp = combo & 3;
  const int ti = ig * 8 + w;                    // i-tile 0..127
  const int n0 = ti << 5;

  const __bf16* qkb = qkpk + (size_t)b * 262144;
  const __bf16* vpb = vpk + (size_t)b * 1048576;
  const int jq0 = jp << 10;

  // Q B-frag (lane = col = i), hoisted
  const __bf16* qp = qkb + (size_t)ti * 2048 + h * 256 + l31 * 8;
  const bf16x8 qf0 = *(const bf16x8*)(qp);
  const bf16x8 qf1 = *(const bf16x8*)(qp + 512);

  f32x16 acc[8] = {};                        // [ct] -> c = ct*32 + l31
  float rsum = 0.f;

  const __bf16* kbase = qkb + 1024 + h * 256 + l31 * 8;  // K A-frag base
  const int vfo = h * 2048 + l31 * 8;        // V frag offset within jc-half

  bf16x8 kf0 = *(const bf16x8*)(kbase + (size_t)(jq0 >> 5) * 2048);
  bf16x8 kf1 = *(const bf16x8*)(kbase + (size_t)(jq0 >> 5) * 2048 + 512);

  // ---- prologue: stage V chunk 0 into buf0 ----
  {
    const __bf16* src = vpb + (size_t)(jq0 >> 4) * 4096;
    bf16x8 a = *(const bf16x8*)(src + t * 8);
    bf16x8 c = *(const bf16x8*)(src + 4096 + t * 8);
    *(bf16x8*)(Vbuf + t * 8) = a;
    *(bf16x8*)(Vbuf + 4096 + t * 8) = c;
  }
  sync_lds();

  // ---- main loop: 32 chunks of 32 j ----
#pragma unroll 1
  for (int ch = 0; ch < 32; ++ch) {
    // issue stage loads for chunk ch+1 (write happens at bottom - T14)
    bf16x8 sv0, sv1;
    if (ch < 31) {
      const __bf16* src = vpb + (size_t)((jq0 >> 4) + (ch + 1) * 2) * 4096;
      sv0 = *(const bf16x8*)(src + t * 8);
      sv1 = *(const bf16x8*)(src + 4096 + t * 8);
    }

    // spine: S^T = mfma(K,Q), lane holds P row for i = l31
    f32x16 s = {};
    s = mfma32(kf0, qf0, s);
    s = mfma32(kf1, qf1, s);

    if (ch < 31) {  // K prefetch for next chunk
      const __bf16* kp = kbase + (size_t)((jq0 >> 5) + ch + 1) * 2048;
      kf0 = *(const bf16x8*)(kp);
      kf1 = *(const bf16x8*)(kp + 512);
    }

    float p[16];
#pragma unroll
    for (int r = 0; r < 16; r++) { p[r] = __expf(s[r]); rsum += p[r]; }

    // P -> PV A-fragments (cvt_pk + permlane32_swap, T12)
    unsigned int u0 = cvtpk(p[0], p[1]), v0 = cvtpk(p[2], p[3]);
    unsigned int w0 = cvtpk(p[4], p[5]), z0 = cvtpk(p[6], p[7]);
    swap32(u0, w0); swap32(v0, z0);
    unsigned int u1 = cvtpk(p[8], p[9]), v1 = cvtpk(p[10], p[11]);
    unsigned int w1 = cvtpk(p[12], p[13]), z1 = cvtpk(p[14], p[15]);
    swap32(u1, w1); swap32(v1, z1);
    union { unsigned int u[4]; bf16x8 v; } A0, A1;
    A0.u[0] = u0; A0.u[1] = v0; A0.u[2] = w0; A0.u[3] = z0;
    A1.u[0] = u1; A1.u[1] = v1; A1.u[2] = w1; A1.u[3] = z1;

    // PV: V B-frags from LDS buf[ch&1] (ds_read_b128, contiguous per half)
    const __bf16* rb = Vbuf + (ch & 1) * 8192;
#pragma unroll
    for (int ct = 0; ct < 8; ct++) {
      bf16x8 vv = *(const bf16x8*)(rb + vfo + ct * 256);            // jc lo
      acc[ct] = mfma32(A0.v, vv, acc[ct]);
    }
#pragma unroll
    for (int ct = 0; ct < 8; ct++) {
      bf16x8 vv = *(const bf16x8*)(rb + 4096 + vfo + ct * 256);     // jc hi
      acc[ct] = mfma32(A1.v, vv, acc[ct]);
    }

    // write stage -> other buffer (compiler waits vmcnt for sv0/sv1 only;
    // K loads stay in flight), then lgkm-only barrier
    if (ch < 31) {
      __bf16* wb = Vbuf + ((ch + 1) & 1) * 8192;
      *(bf16x8*)(wb + t * 8) = sv0;
      *(bf16x8*)(wb + 4096 + t * 8) = sv1;
    }
    sync_lds();
  }

  // epilogue: wave-local LDS transpose slice [256 c][34 i] = 8704 elems/wave
  __bf16* stage = (__bf16*)smem + (size_t)w * 8704;
#pragma unroll
  for (int ct = 0; ct < 8; ct++) {
    int c0 = ct * 32 + l31;
#pragma unroll
    for (int r = 0; r < 16; r++) {
      int i_loc = (r & 3) + 8 * (r >> 2) + 4 * h;
      stage[c0 * 34 + i_loc] = (__bf16)acc[ct][r];
    }
  }
  asm volatile("s_waitcnt lgkmcnt(0)" ::: "memory");  // wave-local

  // coalesced pO store (u32 = 2 i)
  unsigned short* ob = (unsigned short*)pO + (size_t)(jp * 4 + b) * 1048576 + n0;
  const unsigned short* su = (const unsigned short*)stage;
#pragma unroll 1
  for (int e = l; e < 4096; e += 64) {
    int c = e >> 4, i2 = (e & 15) * 2;
    unsigned int vv = *(const unsigned int*)(su + c * 34 + i2);
    *(unsigned int*)(ob + (size_t)c * 4096 + i2) = vv;
  }

  // rowsum: combine lane halves -> L[i = l31]
  rsum += __shfl_xor(rsum, 32);
  if (l < 32) Lp[(size_t)(jp * 4 + b) * 4096 + n0 + l] = rsum;
}

// ---------------------------------------------------------------------------
// K3: combine partials + normalize + residual.
// ---------------------------------------------------------------------------
__global__ __launch_bounds__(256) void norm_kernel(
    const float* __restrict__ x, const float* __restrict__ gamma_p,
    const __bf16* __restrict__ pO, const float* __restrict__ Lp,
    float* __restrict__ out) {
  const int bc = blockIdx.x;           // b = bc>>8, c = bc&255
  const int b = bc >> 8;
  const float gm = gamma_p[0];
  const float* xr = x + (size_t)bc * 4096;
  float* orow = out + (size_t)bc * 4096;
  const __bf16* pbase = pO + (size_t)bc * 4096;   // +jp*4194304
  const float* lbase = Lp + (size_t)b * 4096;     // +jp*16384

  for (int i0 = threadIdx.x * 4; i0 < 4096; i0 += 1024) {
    float4 xv = *(const float4*)(xr + i0);
    float s0 = 0.f, s1 = 0.f, s2 = 0.f, s3 = 0.f;
    float l0 = 0.f, l1 = 0.f, l2 = 0.f, l3 = 0.f;
#pragma unroll
    for (int jp = 0; jp < 4; jp++) {
      bf16x4 pv = *(const bf16x4*)(pbase + (size_t)jp * 4194304 + i0);
      s0 += (float)pv[0]; s1 += (float)pv[1]; s2 += (float)pv[2]; s3 += (float)pv[3];
      float4 lv = *(const float4*)(lbase + (size_t)jp * 16384 + i0);
      l0 += lv.x; l1 += lv.y; l2 += lv.z; l3 += lv.w;
    }
    float4 ov;
    ov.x = gm * s0 / l0 + xv.x;
    ov.y = gm * s1 / l1 + xv.y;
    ov.z = gm * s2 / l2 + xv.z;
    ov.w = gm * s3 / l3 + xv.w;
    *(float4*)(orow + i0) = ov;
  }
}

// ---------------------------------------------------------------------------
extern "C" void kernel_launch(void* const* d_in, const int* in_sizes, int n_in,
                              void* d_out, int out_size, void* d_ws, size_t ws_size,
                              hipStream_t stream) {
  const float* x   = (const float*)d_in[0];
  const float* Wf  = (const float*)d_in[1];
  const float* bfv = (const float*)d_in[2];
  const float* Wg  = (const float*)d_in[3];
  const float* bgv = (const float*)d_in[4];
  const float* Wh  = (const float*)d_in[5];
  const float* bhv = (const float*)d_in[6];
  const float* gm  = (const float*)d_in[7];
  float* out = (float*)d_out;

  char* ws = (char*)d_ws;
  __bf16* Wb   = (__bf16*)ws;                     //   160 KiB  @ 0
  __bf16* qkpk = (__bf16*)(ws + 262144);          //  2 MiB
  __bf16* vpk  = (__bf16*)(ws + 2359296);         //  8 MiB
  __bf16* pO   = (__bf16*)(ws + 10747904);        // 32 MiB
  float*  Lp   = (float*)(ws + 44302336);         // 256 KiB

  hipLaunchKernelGGL(wcvt_kernel, dim3(320), dim3(256), 0, stream, Wf, Wg, Wh, Wb);
  hipLaunchKernelGGL(proj_kernel, dim3(512), dim3(512), 0, stream,
                     x, bfv, bgv, bhv, Wb, qkpk, vpk);
  hipLaunchKernelGGL(attn_kernel, dim3(256), dim3(512), 0, stream,
                     qkpk, vpk, pO, Lp);
  hipLaunchKernelGGL(norm_kernel, dim3(1024), dim3(256), 0, stream,
                     x, gm, pO, Lp, out);
}